// Round 4
// baseline (329.280 us; speedup 1.0000x reference)
//
#include <hip/hip_runtime.h>

// Problem: B=32, L=4, W=512, D=768, fp32.
// out = [word: B*D*W][sent: B*D]
//   word[b][d][s] = (1/L) * sum_{w: seg[b][w]==s} sum_l emb[b][l][w][d]
//   sent[b][d]    = (1/(W*L)) * sum_{w,l} emb[b][l][w][d]
//
// Single fused kernel. Block = (b, 32-d-tile), 512 threads, processed as TWO
// sequential 16-column passes reusing one LDS tile [16][513] (~35 KB total
// block LDS). Why: the 32-wide tile (68 KB) allowed only 2 resident
// blocks/CU -> 512 slots for 768 uniform blocks -> 1.5-round packing (75%
// utilization). With the half tile, 3 blocks/CU fit -> all 768 blocks
// resident simultaneously -> no packing tail, 24 waves/CU.
// Each pass reads only its own 16 d-columns (64B-aligned sectors, emb still
// read exactly once overall). Segment axis lives in LDS via ds_add_f32 ->
// no global atomics, no workspace, no transpose kernel. Unused segment
// columns stay zero from tile init. Drain writes word rows coalesced.

#define BB 32
#define LL 4
#define WW 512
#define DD 768
#define D4 (DD / 4)
#define WORD_SIZE (BB * DD * WW)

#define DT    32             // d-columns per block (two passes of 16)
#define PD    16             // d-columns per pass
#define NDT   (DD / DT)      // 24 d-tiles -> grid 32*24 = 768 blocks
#define NTHR  512
#define TCOL  513            // padded segment axis (bank = (row + s) % 32)
#define NIT   (WW / 128)     // 4 w-iterations per pass (128 words per step)

__global__ __launch_bounds__(NTHR) void fused(
    const float* __restrict__ emb,   // [B, L, W, D]
    const int*   __restrict__ seg,   // [B, W], sorted, values in [0, W)
    float* __restrict__ word,        // [B, D, W]
    float* __restrict__ sent)        // [B, D]
{
    const int b   = blockIdx.x;
    const int d0  = blockIdx.y * DT;
    const int tid = threadIdx.x;

    __shared__ float tile[PD * TCOL];   // 32,832 B, reused across passes
    __shared__ float sentbuf[DT];
    __shared__ int   seg_sh[WW];

    if (tid < DT) sentbuf[tid] = 0.f;
    seg_sh[tid] = seg[b * WW + tid];

    // thread geometry: di4 = float4 column within the 16-col pass (0..3),
    // p = word-phase (0..127). Wave = 16 consecutive words x 4 lanes (64B).
    const int p   = tid >> 2;
    const int di4 = tid & 3;
    const float4* e4 = (const float4*)emb;
    const size_t lstride = (size_t)WW * D4;

#pragma unroll
    for (int pass = 0; pass < 2; ++pass) {
        const int dbase = d0 + pass * PD;

        // ---- init tile ----
        for (int i = tid; i < PD * TCOL; i += NTHR) tile[i] = 0.f;
        __syncthreads();

        // ---- stream + scatter ----
        const size_t base = (size_t)b * LL * WW * D4 + (size_t)(dbase / 4) + di4;
        float4 sacc = make_float4(0.f, 0.f, 0.f, 0.f);

#pragma unroll
        for (int it = 0; it < NIT; ++it) {
            const int w = it * 128 + p;
            const size_t off = base + (size_t)w * D4;
            float4 t0 = e4[off];
            float4 t1 = e4[off + lstride];
            float4 t2 = e4[off + 2 * lstride];
            float4 t3 = e4[off + 3 * lstride];
            float4 v;
            v.x = (t0.x + t1.x) + (t2.x + t3.x);
            v.y = (t0.y + t1.y) + (t2.y + t3.y);
            v.z = (t0.z + t1.z) + (t2.z + t3.z);
            v.w = (t0.w + t1.w) + (t2.w + t3.w);

            sacc.x += v.x; sacc.y += v.y; sacc.z += v.z; sacc.w += v.w;

            const int s = seg_sh[w];
            float* tp = &tile[(di4 * 4) * TCOL + s];
            atomicAdd(tp + 0 * TCOL, v.x);
            atomicAdd(tp + 1 * TCOL, v.y);
            atomicAdd(tp + 2 * TCOL, v.z);
            atomicAdd(tp + 3 * TCOL, v.w);
        }

        // ---- sent partials: reduce over the 16 in-wave word-phases
        // (lane bits 2..5), then one atomic per (wave, di4). ----
#pragma unroll
        for (int m = 4; m <= 32; m <<= 1) {
            sacc.x += __shfl_xor(sacc.x, m);
            sacc.y += __shfl_xor(sacc.y, m);
            sacc.z += __shfl_xor(sacc.z, m);
            sacc.w += __shfl_xor(sacc.w, m);
        }
        if ((tid & 60) == 0) {   // lane p%16==0, one per di4 per wave
            const int sb = pass * PD + di4 * 4;
            atomicAdd(&sentbuf[sb + 0], sacc.x);
            atomicAdd(&sentbuf[sb + 1], sacc.y);
            atomicAdd(&sentbuf[sb + 2], sacc.z);
            atomicAdd(&sentbuf[sb + 3], sacc.w);
        }
        __syncthreads();

        // ---- drain: tile -> word rows (coalesced, already transposed) ----
        float* wout = word + ((size_t)b * DD + dbase) * WW;
#pragma unroll
        for (int k = 0; k < (PD * WW) / NTHR; ++k) {  // 16 stores/thread
            const int flat = k * NTHR + tid;
            const int row  = flat >> 9;               // d within pass
            const int col  = flat & 511;              // s
            wout[(size_t)row * WW + col] = tile[row * TCOL + col] * 0.25f;
        }
        __syncthreads();   // tile reused next pass
    }

    if (tid < DT)
        sent[(size_t)b * DD + d0 + tid] = sentbuf[tid] * (1.0f / (WW * LL));
}

extern "C" void kernel_launch(void* const* d_in, const int* in_sizes, int n_in,
                              void* d_out, int out_size, void* d_ws, size_t ws_size,
                              hipStream_t stream) {
    const float* emb = (const float*)d_in[0];   // [32,4,512,768] fp32
    const int*   seg = (const int*)d_in[1];     // [32,512] int32, sorted per row
    float* out  = (float*)d_out;
    float* word = out;                          // [B, D, W]
    float* sent = out + WORD_SIZE;              // [B, D]
    (void)d_ws; (void)ws_size;                  // no workspace, no memset

    fused<<<dim3(BB, NDT), dim3(NTHR), 0, stream>>>(emb, seg, word, sent);
}